// Round 1
// 485.692 us; speedup vs baseline: 1.0280x; 1.0280x over previous
//
#include <hip/hip_runtime.h>
#include <stdint.h>

#define NN 2048
#define FF 32
#define EE 16
#define KK 32
#define NCOPY 2048                 // pure-copy blocks (odd blockIdx)
#define TOTALB (2 * NN)            // 4096 blocks: parity-interleaved roles

// Heterogeneous grid, 256 threads/block.
//  odd  blocks: stream-copy a 128 KB chunk of edges -> out_edges (no LDS, no barrier)
//  even blocks: per-row compute (adj copy+compaction, sparse message, epilogue)
__global__ __launch_bounds__(256) void gin_fused_kernel(
    const float* __restrict__ adj,     // [N,N]
    const float* __restrict__ nodes,   // [N,F]
    const float* __restrict__ edges,   // [N,N,E]
    const float* __restrict__ W_ne,    // [F+E, F]
    const float* __restrict__ b_ne,    // [F]
    const float* __restrict__ W_n,     // [F,F]
    const float* __restrict__ b_n,     // [F]
    const float* __restrict__ W_net,   // [F,K]
    const float* __restrict__ b_net,   // [K]
    const float* __restrict__ epsp,    // [1]
    float* __restrict__ out_adj,       // [N,N]
    float* __restrict__ out_y,         // [N,K]
    float* __restrict__ out_edges)     // [N,N,E]
{
    const int b   = blockIdx.x;
    const int tid = threadIdx.x;

    if (b & 1) {
        // ---- copy role: pure streaming, saturates HBM while compute blocks
        //      hide their latency underneath ----
        const int cb = b >> 1;                         // 0..NCOPY-1
        const float4* __restrict__ src = (const float4*)edges;
        float4*       __restrict__ dst = (float4*)out_edges;
        const int per  = (NN * NN * EE / 4) / NCOPY;   // 8192 float4 = 128 KB
        const int base = cb * per;
        #pragma unroll 8
        for (int t = tid; t < per; t += 256) dst[base + t] = src[base + t];
        return;
    }

    // ---- compute role: one row i per block ----
    const int i = b >> 1;               // 0..NN-1
    const int f = tid & 31;
    const int g = tid >> 5;             // 0..7

    __shared__ float swe[EE][FF];          // W_ne rows F..F+E  (edge part)
    __shared__ float swn[FF][FF];          // W_ne rows 0..F    (node part)
    __shared__ unsigned short sidx[NN];    // compacted nonzero columns
    __shared__ float sval[NN];             // their adj values
    __shared__ float smsg[FF];
    __shared__ float sh[FF];
    __shared__ int scnt;

    // stage weights to LDS
    for (int t = tid; t < EE * FF; t += 256) swe[t / FF][t % FF] = W_ne[FF * FF + t];
    for (int t = tid; t < FF * FF; t += 256) swn[t / FF][t % FF] = W_ne[t];
    if (tid == 0) scnt = 0;
    if (tid < FF) smsg[tid] = 0.0f;
    __syncthreads();

    const size_t arow = (size_t)i * NN;

    // ---- phase 1: adj row copy (float4) + nonzero compaction ----
    {
        const float4* src = (const float4*)(adj + arow);
        float4* dst = (float4*)(out_adj + arow);
        #pragma unroll
        for (int t = tid; t < NN / 4; t += 256) {
            float4 v = src[t];
            dst[t] = v;
            if (v.x != 0.0f) { int p = atomicAdd(&scnt, 1); sidx[p] = (unsigned short)(t * 4 + 0); sval[p] = v.x; }
            if (v.y != 0.0f) { int p = atomicAdd(&scnt, 1); sidx[p] = (unsigned short)(t * 4 + 1); sval[p] = v.y; }
            if (v.z != 0.0f) { int p = atomicAdd(&scnt, 1); sidx[p] = (unsigned short)(t * 4 + 2); sval[p] = v.z; }
            if (v.w != 0.0f) { int p = atomicAdd(&scnt, 1); sidx[p] = (unsigned short)(t * 4 + 3); sval[p] = v.w; }
        }
    }
    __syncthreads();

    // ---- phase 2: sparse message accumulation (edges read direct from global;
    //      scattered 64 B segments, latency hidden under copy blocks) ----
    const int M = scnt;
    const float bne = b_ne[f];
    float acc = 0.0f;
    for (int n = g; n < M; n += 8) {
        const int j = sidx[n];
        const float a = sval[n];
        // node_part[j][f] : nodes[j,:] (32 f32 = 8 x float4) @ swn[:, f]
        const float4* nr = (const float4*)(nodes + (size_t)j * FF);
        float npv = 0.0f;
        #pragma unroll
        for (int m = 0; m < 8; ++m) {
            float4 q = nr[m];
            npv += q.x * swn[4 * m + 0][f];
            npv += q.y * swn[4 * m + 1][f];
            npv += q.z * swn[4 * m + 2][f];
            npv += q.w * swn[4 * m + 3][f];
        }
        // edge_part[i][j][f] : edges[i,j,:] (16 f32 = 4 x float4) @ swe[:, f]
        const float4* er = (const float4*)(edges + (arow + j) * EE);
        float s = 0.0f;
        #pragma unroll
        for (int m = 0; m < 4; ++m) {
            float4 e = er[m];
            s += e.x * swe[4 * m + 0][f];
            s += e.y * swe[4 * m + 1][f];
            s += e.z * swe[4 * m + 2][f];
            s += e.w * swe[4 * m + 3][f];
        }
        acc += a * fmaxf(npv + s + bne, 0.0f);
    }
    atomicAdd(&smsg[f], acc);
    __syncthreads();

    // ---- phase 3a: h[f] = (1+eps)*relu(nodes[i]@W_n + b_n)[f] + msg[f] ----
    if (tid < FF) {
        const float eps = epsp[0];
        const float* nrow = nodes + (size_t)i * FF;
        float nt = 0.0f;
        #pragma unroll
        for (int e = 0; e < FF; ++e) nt += nrow[e] * W_n[e * FF + f];
        nt = fmaxf(nt + b_n[f], 0.0f);
        sh[f] = (1.0f + eps) * nt + smsg[f];
    }
    __syncthreads();

    // ---- phase 3b: out[i,k] = relu(h @ W_net + b_net) ----
    if (tid < KK) {
        const int k = tid;
        float o = b_net[k];
        #pragma unroll
        for (int ff2 = 0; ff2 < FF; ++ff2) o += sh[ff2] * W_net[ff2 * KK + k];
        out_y[(size_t)i * KK + k] = fmaxf(o, 0.0f);
    }
}

extern "C" void kernel_launch(void* const* d_in, const int* in_sizes, int n_in,
                              void* d_out, int out_size, void* d_ws, size_t ws_size,
                              hipStream_t stream) {
    (void)in_sizes; (void)n_in; (void)out_size; (void)d_ws; (void)ws_size;
    const float* adj   = (const float*)d_in[0];
    const float* nodes = (const float*)d_in[1];
    const float* edges = (const float*)d_in[2];
    const float* W_ne  = (const float*)d_in[3];
    const float* b_ne  = (const float*)d_in[4];
    const float* W_n   = (const float*)d_in[5];
    const float* b_n   = (const float*)d_in[6];
    const float* W_net = (const float*)d_in[7];
    const float* b_net = (const float*)d_in[8];
    const float* epsp  = (const float*)d_in[9];

    float* out       = (float*)d_out;
    float* out_adj   = out;                                      // N*N
    float* out_y     = out + (size_t)NN * NN;                    // N*K
    float* out_edges = out + (size_t)NN * NN + (size_t)NN * KK;  // N*N*E

    gin_fused_kernel<<<TOTALB, 256, 0, stream>>>(adj, nodes, edges, W_ne, b_ne, W_n, b_n,
                                                 W_net, b_net, epsp,
                                                 out_adj, out_y, out_edges);
}